// Round 1
// 6709.522 us; speedup vs baseline: 1.1208x; 1.1208x over previous
//
#include <hip/hip_runtime.h>
#include <hip/hip_bf16.h>
#include <cstdint>
#include <cstddef>

#define T_STEPS 256
#define BATCH   512
#define DIM     512
#define HID     512
#define NQV     8
#define KDIM    1024
#define NPACK   2064   // 32 h-blocks * 64 gate cols + 16 q cols (8 real + 8 pad)
#define ALPHA_C 0.7f

typedef __bf16 bf16x8 __attribute__((ext_vector_type(8)));
typedef float  f32x4  __attribute__((ext_vector_type(4)));

// ---------------- prep kernels ----------------

__global__ void zero_kernel(uint32_t* p, int n) {
    int i = blockIdx.x * 256 + threadIdx.x;
    if (i < n) p[i] = 0u;
}

// Wt layout: (NPACK rows, KDIM cols) bf16, row-major (k contiguous).
// n in [0,2048): j=n>>6 (h-block), c=n&63, gate=c>>4, h=16j+(c&15): Wt[n][k]=W_g[k][h]
// n in [2048,2056): Wt[n][k]=Wq[k][n-2048];  n in [2056,2064): 0
__global__ void pack_w_kernel(const float* __restrict__ Wf, const float* __restrict__ Wi,
                              const float* __restrict__ Wu, const float* __restrict__ Wo,
                              const float* __restrict__ Wq, __bf16* __restrict__ Wt) {
    int idx = blockIdx.x * 256 + threadIdx.x;   // grid covers NPACK*KDIM exactly
    int n = idx >> 10;
    int k = idx & 1023;
    float v = 0.0f;
    if (n < 2048) {
        int j = n >> 6, c = n & 63, g = c >> 4;
        int hh = (j << 4) | (c & 15);
        const float* W = (g == 0) ? Wf : (g == 1) ? Wi : (g == 2) ? Wu : Wo;
        v = W[k * HID + hh];
    } else if (n < 2056) {
        v = Wq[k * NQV + (n - 2048)];
    }
    Wt[idx] = (__bf16)v;
}

// WqhT: (HID, 8) bf16, row h holds Wqh[0..7][h]
__global__ void pack_wqh_kernel(const float* __restrict__ Wqh, __bf16* __restrict__ WqhT) {
    int idx = blockIdx.x * 256 + threadIdx.x;
    if (idx < HID * NQV) {
        int h = idx >> 3, w = idx & 7;
        WqhT[idx] = (__bf16)Wqh[w * HID + h];
    }
}

// ---------------- hoisted x-GEMM (time-parallel, no recurrence dependence) ----------------
// XW[t_local][n][b] = sum_{k<512} X[tc+t_local][b][k] * Wt[n][k]   (f32, b contiguous)
// Block: 128 batch-rows (2 sub-tiles of 64) x 80 packed cols; 4 waves; K=512.
// Bit-identical to the old kernel's phase-1 accumulation (same MFMA order over k).
__global__ __launch_bounds__(256)
void prep_kernel(int tc, const float* __restrict__ X, const __bf16* __restrict__ Wt,
                 float* __restrict__ XW)
{
    const int rbb = blockIdx.x;           // 128-row group within chunk
    const int j   = blockIdx.y;           // 0..31
    const int tid = threadIdx.x;
    const int w = tid >> 6, l = tid & 63, lrow = l & 15, lk = l >> 4;

    const int row0 = rbb * 128;           // chunk-local row (128 | 512 -> single t)
    const int tl   = row0 >> 9;
    const int bb   = row0 & 511;

    const float* ap0 = X + ((size_t)(tc + tl) * BATCH + (bb + w * 16 + lrow)) * DIM + lk * 8;
    const float* ap1 = ap0 + (size_t)64 * DIM;

    const __bf16* bp0 = Wt + (size_t)(j * 64 +  0 + lrow) * KDIM + lk * 8;
    const __bf16* bp1 = Wt + (size_t)(j * 64 + 16 + lrow) * KDIM + lk * 8;
    const __bf16* bp2 = Wt + (size_t)(j * 64 + 32 + lrow) * KDIM + lk * 8;
    const __bf16* bp3 = Wt + (size_t)(j * 64 + 48 + lrow) * KDIM + lk * 8;
    const __bf16* bp4 = Wt + (size_t)(2048     + lrow) * KDIM + lk * 8;

    f32x4 acc0[5] = {};
    f32x4 acc1[5] = {};

    #pragma unroll 2
    for (int ks = 0; ks < 16; ++ks) {
        float4 x0 = *(const float4*)(ap0 + ks * 32);
        float4 x1 = *(const float4*)(ap0 + ks * 32 + 4);
        float4 y0 = *(const float4*)(ap1 + ks * 32);
        float4 y1 = *(const float4*)(ap1 + ks * 32 + 4);
        bf16x8 a0, a1;
        a0[0] = (__bf16)x0.x; a0[1] = (__bf16)x0.y; a0[2] = (__bf16)x0.z; a0[3] = (__bf16)x0.w;
        a0[4] = (__bf16)x1.x; a0[5] = (__bf16)x1.y; a0[6] = (__bf16)x1.z; a0[7] = (__bf16)x1.w;
        a1[0] = (__bf16)y0.x; a1[1] = (__bf16)y0.y; a1[2] = (__bf16)y0.z; a1[3] = (__bf16)y0.w;
        a1[4] = (__bf16)y1.x; a1[5] = (__bf16)y1.y; a1[6] = (__bf16)y1.z; a1[7] = (__bf16)y1.w;
        bf16x8 b0 = *(const bf16x8*)(bp0 + ks * 32);
        bf16x8 b1 = *(const bf16x8*)(bp1 + ks * 32);
        bf16x8 b2 = *(const bf16x8*)(bp2 + ks * 32);
        bf16x8 b3 = *(const bf16x8*)(bp3 + ks * 32);
        bf16x8 b4 = *(const bf16x8*)(bp4 + ks * 32);
        acc0[0] = __builtin_amdgcn_mfma_f32_16x16x32_bf16(a0, b0, acc0[0], 0, 0, 0);
        acc1[0] = __builtin_amdgcn_mfma_f32_16x16x32_bf16(a1, b0, acc1[0], 0, 0, 0);
        acc0[1] = __builtin_amdgcn_mfma_f32_16x16x32_bf16(a0, b1, acc0[1], 0, 0, 0);
        acc1[1] = __builtin_amdgcn_mfma_f32_16x16x32_bf16(a1, b1, acc1[1], 0, 0, 0);
        acc0[2] = __builtin_amdgcn_mfma_f32_16x16x32_bf16(a0, b2, acc0[2], 0, 0, 0);
        acc1[2] = __builtin_amdgcn_mfma_f32_16x16x32_bf16(a1, b2, acc1[2], 0, 0, 0);
        acc0[3] = __builtin_amdgcn_mfma_f32_16x16x32_bf16(a0, b3, acc0[3], 0, 0, 0);
        acc1[3] = __builtin_amdgcn_mfma_f32_16x16x32_bf16(a1, b3, acc1[3], 0, 0, 0);
        acc0[4] = __builtin_amdgcn_mfma_f32_16x16x32_bf16(a0, b4, acc0[4], 0, 0, 0);
        acc1[4] = __builtin_amdgcn_mfma_f32_16x16x32_bf16(a1, b4, acc1[4], 0, 0, 0);
    }

    // C-frag: row(batch) = lk*4+r, col(n) = lrow -> f32x4 store is contiguous in b
    const int brow = bb + w * 16 + lk * 4;
    #pragma unroll
    for (int g = 0; g < 4; ++g) {
        float* p = XW + ((size_t)tl * NPACK + (j * 64 + g * 16 + lrow)) * BATCH + brow;
        __builtin_nontemporal_store(acc0[g], (f32x4*)p);
        __builtin_nontemporal_store(acc1[g], (f32x4*)(p + 64));
    }
    if (j == 0) {   // q cols identical for every j-block: store once
        float* p = XW + ((size_t)tl * NPACK + (2048 + lrow)) * BATCH + brow;
        __builtin_nontemporal_store(acc0[4], (f32x4*)p);
        __builtin_nontemporal_store(acc1[4], (f32x4*)(p + 64));
    }
}

// ---------------- step kernel ----------------

__device__ __forceinline__ float sigf(float x) {
    return __builtin_amdgcn_rcpf(1.0f + __expf(-x));
}
__device__ __forceinline__ float tanhf_fast(float x) {
    float ax = fabsf(x);
    float e  = __expf(-2.0f * ax);
    float r  = (1.0f - e) * __builtin_amdgcn_rcpf(1.0f + e);
    return copysignf(r, x);
}

// MODE 1: hoisted — acc init from XW, K-loop only over hx (k 512..1023), split 2-way.
// MODE 0: fallback — full K in-kernel (kh=0: x from f32; kh=1: hx), split 2-way.
// 512 threads = 8 waves: wm = w&3 selects the 16-row group, kh = w>>2 the K half.
// 2 waves/SIMD (vs 1 before) + half the serial load chain per wave.
template <int MODE>
__global__ __launch_bounds__(512)
void step_kernel(int t,
                 const float* __restrict__ X, const float* __restrict__ XW,
                 const __bf16* __restrict__ Wt, const __bf16* __restrict__ WqhT,
                 const float* __restrict__ bf_, const float* __restrict__ bi_,
                 const float* __restrict__ bu_, const float* __restrict__ bo_,
                 const float* __restrict__ bq_, const float* __restrict__ bqh_,
                 const float* __restrict__ thf, const float* __restrict__ thi,
                 const float* __restrict__ thu, const float* __restrict__ tho,
                 __bf16* __restrict__ hxbf, float* __restrict__ cx,
                 float* __restrict__ out)
{
    const int j    = blockIdx.x;   // h-block: h in [16j, 16j+16)
    const int rb   = blockIdx.y;   // rows [64rb, 64rb+64)
    const int tid  = threadIdx.x;
    const int w    = tid >> 6;
    const int l    = tid & 63;
    const int lrow = l & 15;
    const int lk   = l >> 4;       // 0..3
    const int wm   = w & 3;        // row-wave 0..3
    const int kh   = w >> 2;       // K half 0/1

    const int ar = rb * 64 + wm * 16 + lrow;   // A row (batch index)

    f32x4 acc[5] = {};
    f32x4 xwf[5] = {};

    // issue XW prefetch FIRST (HBM/L3 latency hides under the K-loop; joined after it)
    if (MODE == 1 && kh == 0) {
        const int b0 = rb * 64 + wm * 16 + lk * 4;
        #pragma unroll
        for (int g = 0; g < 4; ++g)
            xwf[g] = *(const f32x4*)(XW + (size_t)(j * 64 + g * 16 + lrow) * BATCH + b0);
        xwf[4] = *(const f32x4*)(XW + (size_t)(2048 + lrow) * BATCH + b0);
    }

    const int koff = MODE ? (512 + kh * 256) : (kh * 512);
    const __bf16* bp0 = Wt + (size_t)(j * 64 +  0 + lrow) * KDIM + koff + lk * 8;
    const __bf16* bp1 = Wt + (size_t)(j * 64 + 16 + lrow) * KDIM + koff + lk * 8;
    const __bf16* bp2 = Wt + (size_t)(j * 64 + 32 + lrow) * KDIM + koff + lk * 8;
    const __bf16* bp3 = Wt + (size_t)(j * 64 + 48 + lrow) * KDIM + koff + lk * 8;
    const __bf16* bp4 = Wt + (size_t)(2048     + lrow) * KDIM + koff + lk * 8;

    if (MODE == 0 && kh == 0) {
        // x phase from f32 (fallback only)
        const float* aptr = X + ((size_t)t * BATCH + ar) * DIM + lk * 8;
        #pragma unroll 4
        for (int ks = 0; ks < 16; ++ks) {
            float4 x0 = *(const float4*)(aptr + ks * 32);
            float4 x1 = *(const float4*)(aptr + ks * 32 + 4);
            bf16x8 a;
            a[0] = (__bf16)x0.x; a[1] = (__bf16)x0.y; a[2] = (__bf16)x0.z; a[3] = (__bf16)x0.w;
            a[4] = (__bf16)x1.x; a[5] = (__bf16)x1.y; a[6] = (__bf16)x1.z; a[7] = (__bf16)x1.w;
            bf16x8 b0 = *(const bf16x8*)(bp0 + ks * 32);
            bf16x8 b1 = *(const bf16x8*)(bp1 + ks * 32);
            bf16x8 b2 = *(const bf16x8*)(bp2 + ks * 32);
            bf16x8 b3 = *(const bf16x8*)(bp3 + ks * 32);
            bf16x8 b4 = *(const bf16x8*)(bp4 + ks * 32);
            acc[0] = __builtin_amdgcn_mfma_f32_16x16x32_bf16(a, b0, acc[0], 0, 0, 0);
            acc[1] = __builtin_amdgcn_mfma_f32_16x16x32_bf16(a, b1, acc[1], 0, 0, 0);
            acc[2] = __builtin_amdgcn_mfma_f32_16x16x32_bf16(a, b2, acc[2], 0, 0, 0);
            acc[3] = __builtin_amdgcn_mfma_f32_16x16x32_bf16(a, b3, acc[3], 0, 0, 0);
            acc[4] = __builtin_amdgcn_mfma_f32_16x16x32_bf16(a, b4, acc[4], 0, 0, 0);
        }
    } else {
        // hx phase (MODE1: 8 k-steps per half; MODE0 kh==1: 16 k-steps)
        const int nks = MODE ? 8 : 16;
        const __bf16* aptr = hxbf + (size_t)ar * HID + (MODE ? kh * 256 : 0) + lk * 8;
        #pragma unroll
        for (int ks = 0; ks < nks; ++ks) {
            bf16x8 a  = *(const bf16x8*)(aptr + ks * 32);
            bf16x8 b0 = *(const bf16x8*)(bp0 + ks * 32);
            bf16x8 b1 = *(const bf16x8*)(bp1 + ks * 32);
            bf16x8 b2 = *(const bf16x8*)(bp2 + ks * 32);
            bf16x8 b3 = *(const bf16x8*)(bp3 + ks * 32);
            bf16x8 b4 = *(const bf16x8*)(bp4 + ks * 32);
            acc[0] = __builtin_amdgcn_mfma_f32_16x16x32_bf16(a, b0, acc[0], 0, 0, 0);
            acc[1] = __builtin_amdgcn_mfma_f32_16x16x32_bf16(a, b1, acc[1], 0, 0, 0);
            acc[2] = __builtin_amdgcn_mfma_f32_16x16x32_bf16(a, b2, acc[2], 0, 0, 0);
            acc[3] = __builtin_amdgcn_mfma_f32_16x16x32_bf16(a, b3, acc[3], 0, 0, 0);
            acc[4] = __builtin_amdgcn_mfma_f32_16x16x32_bf16(a, b4, acc[4], 0, 0, 0);
        }
    }

    // join hoisted x-part
    if (MODE == 1 && kh == 0) {
        #pragma unroll
        for (int g = 0; g < 5; ++g) acc[g] += xwf[g];
    }

    // ---- K-split reduction: waves kh==1 -> LDS -> waves kh==0 ----
    __shared__ float part[20][256];    // [g*4+r][wm*64+l], lane-stride 4B: conflict-free
    if (kh == 1) {
        #pragma unroll
        for (int g = 0; g < 5; ++g)
            #pragma unroll
            for (int r = 0; r < 4; ++r)
                part[g * 4 + r][wm * 64 + l] = acc[g][r];
    }
    __syncthreads();
    if (kh == 0) {
        #pragma unroll
        for (int g = 0; g < 5; ++g)
            #pragma unroll
            for (int r = 0; r < 4; ++r)
                acc[g][r] += part[g * 4 + r][wm * 64 + l];
    }

    // ---- epilogue: q-layer (cumprod of cos) + 4 masked MFMAs + cell update ----
    __shared__ __align__(16) float          qin[64][8];
    __shared__ __align__(16) unsigned short cumbf[64][4][8];

    // scatter q_in C-frag (acc[4], valid cols 0..7) to LDS; D row = lk*4+r, col = lrow
    if (kh == 0 && lrow < 8) {
        #pragma unroll
        for (int r = 0; r < 4; ++r)
            qin[wm * 16 + lk * 4 + r][lrow] = acc[4][r];
    }
    __syncthreads();

    // each lane of waves 0-3: one (row, gate): 8 cos + cumprod, write bf16x8
    if (kh == 0) {
        const int row = wm * 16 + lrow;
        const int g   = lk;
        const float* th = (g == 0) ? thf : (g == 1) ? thi : (g == 2) ? thu : tho;
        float cp = 1.0f;
        bf16x8 cv;
        #pragma unroll
        for (int q = 0; q < 8; ++q) {
            float qv = qin[row][q] + bq_[q] + th[q];
            cp *= __cosf(qv);
            cv[q] = (__bf16)cp;
        }
        *(bf16x8*)(&cumbf[row][g][0]) = cv;
    }
    __syncthreads();

    if (kh == 0) {
        // A2-frag: lane l -> cum[row=16wm+(l&15)][gate=l>>4][w=0..7] : exact A-layout match
        bf16x8 a2 = *(const bf16x8*)(&cumbf[wm * 16 + lrow][lk][0]);
        bf16x8 wq = *(const bf16x8*)(WqhT + (size_t)(j * 16 + lrow) * 8);
        bf16x8 zv = {};
        f32x4 vacc[4];
        #pragma unroll
        for (int g = 0; g < 4; ++g) {
            bf16x8 bg = (lk == g) ? wq : zv;   // block-diagonal B: isolate gate g's K rows
            f32x4 z = {};
            vacc[g] = __builtin_amdgcn_mfma_f32_16x16x32_bf16(a2, bg, z, 0, 0, 0);
        }

        const int   h   = j * 16 + lrow;
        const float bfv = bf_[h], biv = bi_[h], buv = bu_[h], bov = bo_[h], bqv = bqh_[h];

        #pragma unroll
        for (int r = 0; r < 4; ++r) {
            const int    b  = rb * 64 + wm * 16 + lk * 4 + r;
            const size_t ch = (size_t)b * HID + h;
            float f  = ALPHA_C * sigf(acc[0][r] + bfv) + (1.0f - ALPHA_C) * sigf(vacc[0][r] + bqv);
            float i_ = ALPHA_C * sigf(acc[1][r] + biv) + (1.0f - ALPHA_C) * sigf(vacc[1][r] + bqv);
            float g_ = ALPHA_C * tanhf_fast(acc[2][r] + buv) + (1.0f - ALPHA_C) * tanhf_fast(vacc[2][r] + bqv);
            float o_ = ALPHA_C * sigf(acc[3][r] + bov) + (1.0f - ALPHA_C) * sigf(vacc[3][r] + bqv);
            float cn = f * cx[ch] + i_ * g_;
            float hn = o_ * tanhf_fast(cn);
            cx[ch]   = cn;
            hxbf[ch] = (__bf16)hn;
            __builtin_nontemporal_store(hn, out + (size_t)t * (BATCH * HID) + ch);
        }
    }
}

// ---------------- launch ----------------

extern "C" void kernel_launch(void* const* d_in, const int* in_sizes, int n_in,
                              void* d_out, int out_size, void* d_ws, size_t ws_size,
                              hipStream_t stream) {
    const float* X   = (const float*)d_in[0];
    const float* Wf  = (const float*)d_in[1];
    const float* bf_ = (const float*)d_in[2];
    const float* Wi  = (const float*)d_in[3];
    const float* bi  = (const float*)d_in[4];
    const float* Wu  = (const float*)d_in[5];
    const float* bu  = (const float*)d_in[6];
    const float* Wo  = (const float*)d_in[7];
    const float* bo  = (const float*)d_in[8];
    const float* Wq  = (const float*)d_in[9];
    const float* bq  = (const float*)d_in[10];
    const float* Wqh = (const float*)d_in[11];
    const float* bqh = (const float*)d_in[12];
    const float* thf = (const float*)d_in[13];
    const float* thi = (const float*)d_in[14];
    const float* thu = (const float*)d_in[15];
    const float* tho = (const float*)d_in[16];
    float* out = (float*)d_out;

    char*  ws  = (char*)d_ws;
    size_t off = 0;
    auto alloc = [&](size_t bytes) -> char* {
        char* p = ws + off;
        off += (bytes + 255) & ~(size_t)255;
        return p;
    };
    __bf16* Wt   = (__bf16*)alloc((size_t)NPACK * KDIM * 2);
    __bf16* WqhT = (__bf16*)alloc((size_t)HID * NQV * 2);
    float*  cx   = (float*) alloc((size_t)BATCH * HID * 4);
    __bf16* hxbf = (__bf16*)alloc((size_t)BATCH * HID * 2);
    size_t base_end = off;

    // pick the largest timestep-chunk for the hoisted x-GEMM that fits the workspace;
    // CH<=16 keeps the 67MB chunk L3-resident between producer and consumers
    const int chs[5] = {16, 8, 4, 2, 1};
    int CH = 0;
    for (int ci = 0; ci < 5; ++ci) {
        size_t need = (size_t)chs[ci] * NPACK * BATCH * 4;
        if (base_end + need <= ws_size) { CH = chs[ci]; break; }
    }
    float* XW = (CH > 0) ? (float*)alloc((size_t)CH * NPACK * BATCH * 4) : nullptr;

    // init state (ws is poisoned 0xAA before every call)
    zero_kernel<<<dim3((BATCH * HID) / 256), dim3(256), 0, stream>>>((uint32_t*)cx, BATCH * HID);
    zero_kernel<<<dim3((BATCH * HID / 2) / 256), dim3(256), 0, stream>>>((uint32_t*)hxbf, BATCH * HID / 2);

    pack_w_kernel<<<dim3((NPACK * KDIM) / 256), dim3(256), 0, stream>>>(Wf, Wi, Wu, Wo, Wq, Wt);
    pack_wqh_kernel<<<dim3((HID * NQV + 255) / 256), dim3(256), 0, stream>>>(Wqh, WqhT);

    dim3 grid(32, 8), block(512);
    const size_t xw_stride = (size_t)NPACK * BATCH;

    if (CH > 0) {
        for (int c = 0; c < T_STEPS / CH; ++c) {
            prep_kernel<<<dim3(CH * 4, 32), dim3(256), 0, stream>>>(c * CH, X, Wt, XW);
            for (int t = c * CH; t < (c + 1) * CH; ++t)
                step_kernel<1><<<grid, block, 0, stream>>>(t, X, XW + (size_t)(t - c * CH) * xw_stride,
                    Wt, WqhT, bf_, bi, bu, bo, bq, bqh, thf, thi, thu, tho, hxbf, cx, out);
        }
    } else {
        for (int t = 0; t < T_STEPS; ++t)
            step_kernel<0><<<grid, block, 0, stream>>>(t, X, nullptr,
                Wt, WqhT, bf_, bi, bu, bo, bq, bqh, thf, thi, thu, tho, hxbf, cx, out);
    }

    // tail outputs: hx = out[T-1], cx
    const size_t BH = (size_t)BATCH * HID;
    hipMemcpyAsync(out + (size_t)T_STEPS * BH, out + (size_t)(T_STEPS - 1) * BH,
                   BH * sizeof(float), hipMemcpyDeviceToDevice, stream);
    hipMemcpyAsync(out + (size_t)T_STEPS * BH + BH, cx,
                   BH * sizeof(float), hipMemcpyDeviceToDevice, stream);
    (void)in_sizes; (void)n_in; (void)out_size;
}

// Round 2
// 5490.783 us; speedup vs baseline: 1.3695x; 1.2220x over previous
//
#include <hip/hip_runtime.h>
#include <hip/hip_bf16.h>
#include <cstdint>
#include <cstddef>

#define T_STEPS 256
#define BATCH   512
#define DIM     512
#define HID     512
#define NQV     8
#define ALPHA_C 0.7f
#define NBLK    256
#define LDSW    520   // padded LDS row stride (elements): 1040B rows -> bank-quad rotation

typedef __bf16 bf16x8 __attribute__((ext_vector_type(8)));
typedef float  f32x4  __attribute__((ext_vector_type(4)));

// ---------------- prep kernels ----------------

__global__ void zero_kernel(uint32_t* p, int n) {
    int i = blockIdx.x * 256 + threadIdx.x;
    if (i < n) p[i] = 0u;
}

// Wt2: gate weights in MFMA-fragment order.
// frag element index = (((j*32 + kq)*4 + m)*64 + l)*8 + e
//   value = W_m[k][h], h = j*16 + (l&15), k = kq*32 + (l>>4)*8 + e   (k in [0,1024))
// One thread per frag-lane (writes 8 contiguous bf16 = 16B).
__global__ void pack_w2_kernel(const float* __restrict__ Wf, const float* __restrict__ Wi,
                               const float* __restrict__ Wu, const float* __restrict__ Wo,
                               __bf16* __restrict__ Wt2) {
    int idx = blockIdx.x * 256 + threadIdx.x;     // [0, 32*32*4*64) = [0, 262144)
    int l = idx & 63, m = (idx >> 6) & 3, kq = (idx >> 8) & 31, j = idx >> 13;
    int lrow = l & 15, lk = l >> 4;
    int h = j * 16 + lrow;
    int kb = kq * 32 + lk * 8;
    const float* W = (m == 0) ? Wf : (m == 1) ? Wi : (m == 2) ? Wu : Wo;
    bf16x8 v;
    #pragma unroll
    for (int e = 0; e < 8; ++e) v[e] = (__bf16)W[(size_t)(kb + e) * HID + h];
    *(bf16x8*)(Wt2 + (size_t)idx * 8) = v;
}

// Wtq: q-col weights, frag order: (kq*64 + l)*8 + e ; rows lrow<8 real, else 0-pad
__global__ void pack_wq2_kernel(const float* __restrict__ Wq, __bf16* __restrict__ Wtq) {
    int idx = blockIdx.x * 256 + threadIdx.x;     // [0, 32*64) = [0, 2048)
    int l = idx & 63, kq = idx >> 6;
    int lrow = l & 15, lk = l >> 4;
    int kb = kq * 32 + lk * 8;
    bf16x8 v;
    #pragma unroll
    for (int e = 0; e < 8; ++e)
        v[e] = (lrow < 8) ? (__bf16)Wq[(size_t)(kb + e) * NQV + lrow] : (__bf16)0.0f;
    *(bf16x8*)(Wtq + (size_t)idx * 8) = v;
}

// WqhT: (HID, 8) bf16, row h holds Wqh[0..7][h]
__global__ void pack_wqh_kernel(const float* __restrict__ Wqh, __bf16* __restrict__ WqhT) {
    int idx = blockIdx.x * 256 + threadIdx.x;
    if (idx < HID * NQV) {
        int h = idx >> 3, w = idx & 7;
        WqhT[idx] = (__bf16)Wqh[w * HID + h];
    }
}

// ---------------- device helpers ----------------

__device__ __forceinline__ float sigf(float x) {
    return __builtin_amdgcn_rcpf(1.0f + __expf(-x));
}
__device__ __forceinline__ float tanhf_fast(float x) {
    float ax = fabsf(x);
    float e  = __expf(-2.0f * ax);
    float r  = (1.0f - e) * __builtin_amdgcn_rcpf(1.0f + e);
    return copysignf(r, x);
}

// ---------------- persistent kernel ----------------
// grid = 256 blocks (j = bid&31 h-tile, rb = bid>>5 batch-tile), 512 threads = 8 waves.
// LDS 107 KB > 80 KB forces 1 block/CU -> all 256 blocks co-resident on 256 CUs.
// Per step: hx-GEMM (B from LDS, staged once) -> epilogue (cx in regs) -> barrier-arrive
// -> shadow x-GEMM for t+1 (no hx dep; overlaps barrier) -> gate-wait.
__global__ __launch_bounds__(512, 2)
void qlstm_persistent(const float* __restrict__ X,
                      const __bf16* __restrict__ Wt2, const __bf16* __restrict__ Wtq,
                      const __bf16* __restrict__ WqhT,
                      const float* __restrict__ bf_, const float* __restrict__ bi_,
                      const float* __restrict__ bu_, const float* __restrict__ bo_,
                      const float* __restrict__ bq_, const float* __restrict__ bqh_,
                      const float* __restrict__ thf, const float* __restrict__ thi,
                      const float* __restrict__ thu, const float* __restrict__ tho,
                      __bf16* __restrict__ hx0, __bf16* __restrict__ hx1,
                      int* __restrict__ bar,            // [0..7]*32 cnt, [256] cnt2, [288] gate
                      float* __restrict__ out)
{
    const int j    = blockIdx.x & 31;
    const int rb   = blockIdx.x >> 5;
    const int tid  = threadIdx.x;
    const int w    = tid >> 6;
    const int l    = tid & 63;
    const int lrow = l & 15;
    const int lk   = l >> 4;
    const int wm   = w & 3;       // row-wave
    const int kh   = w >> 2;      // K half
    const int ar   = rb * 64 + wm * 16 + lrow;

    __shared__ __align__(16) __bf16         whh[80 * LDSW];       // 83200 B
    __shared__ float                        part[20][256];        // 20480 B
    __shared__ __align__(16) float          qin[64][8];           // 2048 B
    __shared__ __align__(16) unsigned short cumbf[64][4][8];      // 4096 B

    // ---- one-time: stage Whh (global k 512..1023, 64 gate rows + 16 q rows) to LDS ----
    for (int f = w; f < 80; f += 8) {
        int kq16 = f / 5, mm = f % 5;                 // kq = 16 + kq16
        const __bf16* src = (mm < 4)
            ? Wt2 + ((((size_t)(j * 32 + 16 + kq16) * 4 + mm) * 64 + l) * 8)
            : Wtq + (((size_t)(16 + kq16) * 64 + l) * 8);
        bf16x8 v = *(const bf16x8*)src;
        int row = (mm < 4 ? mm * 16 : 64) + lrow;
        int col = kq16 * 32 + lk * 8;
        *(bf16x8*)(whh + row * LDSW + col) = v;
    }

    // ---- one-time: per-lane constants ----
    const int   h   = j * 16 + lrow;
    const float bfv = bf_[h], biv = bi_[h], buv = bu_[h], bov = bo_[h], bqv = bqh_[h];
    const float* thp = (lk == 0) ? thf : (lk == 1) ? thi : (lk == 2) ? thu : tho;
    float thr[8], bqr[8];
    #pragma unroll
    for (int q = 0; q < 8; ++q) { thr[q] = thp[q]; bqr[q] = bq_[q]; }
    const bf16x8 wqf = *(const bf16x8*)(WqhT + (size_t)h * 8);
    const bf16x8 zv  = {};

    float cxr[4] = {0.0f, 0.0f, 0.0f, 0.0f};          // cell state, register-resident

    __syncthreads();   // whh staged

    // x-GEMM (k = kh*256 .. +256) into xa[5]; A = X[tt] f32->bf16, B = Wt2/Wtq frags (coalesced)
    const __bf16* gbase = Wt2 + (size_t)j * 65536 + (size_t)kh * 8 * 2048 + (size_t)l * 8;
    const __bf16* qbase = Wtq + (size_t)kh * 8 * 512 + (size_t)l * 8;
    auto xgemm = [&](int tt, f32x4* xa) {
        const float* ap = X + ((size_t)tt * BATCH + ar) * DIM + kh * 256 + lk * 8;
        #pragma unroll 4
        for (int ks = 0; ks < 8; ++ks) {
            float4 x0 = *(const float4*)(ap + ks * 32);
            float4 x1 = *(const float4*)(ap + ks * 32 + 4);
            bf16x8 a;
            a[0] = (__bf16)x0.x; a[1] = (__bf16)x0.y; a[2] = (__bf16)x0.z; a[3] = (__bf16)x0.w;
            a[4] = (__bf16)x1.x; a[5] = (__bf16)x1.y; a[6] = (__bf16)x1.z; a[7] = (__bf16)x1.w;
            const __bf16* gf = gbase + (size_t)ks * 2048;
            bf16x8 b0 = *(const bf16x8*)(gf);
            bf16x8 b1 = *(const bf16x8*)(gf + 512);
            bf16x8 b2 = *(const bf16x8*)(gf + 1024);
            bf16x8 b3 = *(const bf16x8*)(gf + 1536);
            bf16x8 b4 = *(const bf16x8*)(qbase + (size_t)ks * 512);
            xa[0] = __builtin_amdgcn_mfma_f32_16x16x32_bf16(a, b0, xa[0], 0, 0, 0);
            xa[1] = __builtin_amdgcn_mfma_f32_16x16x32_bf16(a, b1, xa[1], 0, 0, 0);
            xa[2] = __builtin_amdgcn_mfma_f32_16x16x32_bf16(a, b2, xa[2], 0, 0, 0);
            xa[3] = __builtin_amdgcn_mfma_f32_16x16x32_bf16(a, b3, xa[3], 0, 0, 0);
            xa[4] = __builtin_amdgcn_mfma_f32_16x16x32_bf16(a, b4, xa[4], 0, 0, 0);
        }
    };

    f32x4 xacc[5] = {};
    xgemm(0, xacc);                                    // step-0 x-part, pre-barrier

    int* cnt_slot = bar + (blockIdx.x & 7) * 32;
    int* cnt2     = bar + 256;
    int* gate     = bar + 288;
    const size_t BH = (size_t)BATCH * HID;

    for (int t = 0; t < T_STEPS; ++t) {
        f32x4 acc[5];
        #pragma unroll
        for (int g = 0; g < 5; ++g) acc[g] = xacc[g];

        if (t > 0) {
            // hx-GEMM: A from global hx (prev buffer), B from LDS whh
            const __bf16* rbuf = ((t - 1) & 1) ? hx1 : hx0;
            const __bf16* ap   = rbuf + (size_t)ar * HID + kh * 256 + lk * 8;
            #pragma unroll
            for (int ks = 0; ks < 8; ++ks) {
                bf16x8 a = *(const bf16x8*)(ap + ks * 32);
                const int kcol = kh * 256 + ks * 32 + lk * 8;
                bf16x8 b0 = *(const bf16x8*)(whh + ( 0 + lrow) * LDSW + kcol);
                bf16x8 b1 = *(const bf16x8*)(whh + (16 + lrow) * LDSW + kcol);
                bf16x8 b2 = *(const bf16x8*)(whh + (32 + lrow) * LDSW + kcol);
                bf16x8 b3 = *(const bf16x8*)(whh + (48 + lrow) * LDSW + kcol);
                bf16x8 b4 = *(const bf16x8*)(whh + (64 + lrow) * LDSW + kcol);
                acc[0] = __builtin_amdgcn_mfma_f32_16x16x32_bf16(a, b0, acc[0], 0, 0, 0);
                acc[1] = __builtin_amdgcn_mfma_f32_16x16x32_bf16(a, b1, acc[1], 0, 0, 0);
                acc[2] = __builtin_amdgcn_mfma_f32_16x16x32_bf16(a, b2, acc[2], 0, 0, 0);
                acc[3] = __builtin_amdgcn_mfma_f32_16x16x32_bf16(a, b3, acc[3], 0, 0, 0);
                acc[4] = __builtin_amdgcn_mfma_f32_16x16x32_bf16(a, b4, acc[4], 0, 0, 0);
            }
        }

        // ---- K-split reduction: kh==1 -> LDS -> kh==0 ----
        if (kh == 1) {
            #pragma unroll
            for (int g = 0; g < 5; ++g)
                #pragma unroll
                for (int r = 0; r < 4; ++r)
                    part[g * 4 + r][wm * 64 + l] = acc[g][r];
        }
        __syncthreads();
        if (kh == 0) {
            #pragma unroll
            for (int g = 0; g < 5; ++g)
                #pragma unroll
                for (int r = 0; r < 4; ++r)
                    acc[g][r] += part[g * 4 + r][wm * 64 + l];
        }

        // ---- epilogue ----
        if (kh == 0 && lrow < 8) {
            #pragma unroll
            for (int r = 0; r < 4; ++r)
                qin[wm * 16 + lk * 4 + r][lrow] = acc[4][r];
        }
        __syncthreads();

        if (kh == 0) {
            const int row = wm * 16 + lrow;
            float cp = 1.0f;
            bf16x8 cv;
            #pragma unroll
            for (int q = 0; q < 8; ++q) {
                float qv = qin[row][q] + bqr[q] + thr[q];
                cp *= __cosf(qv);
                cv[q] = (__bf16)cp;
            }
            *(bf16x8*)(&cumbf[row][lk][0]) = cv;
        }
        __syncthreads();

        if (kh == 0) {
            bf16x8 a2 = *(const bf16x8*)(&cumbf[wm * 16 + lrow][lk][0]);
            f32x4 vacc[4];
            #pragma unroll
            for (int g = 0; g < 4; ++g) {
                bf16x8 bg = (lk == g) ? wqf : zv;
                f32x4 z = {};
                vacc[g] = __builtin_amdgcn_mfma_f32_16x16x32_bf16(a2, bg, z, 0, 0, 0);
            }

            __bf16* wbuf = (t & 1) ? hx1 : hx0;
            #pragma unroll
            for (int r = 0; r < 4; ++r) {
                const int    b  = rb * 64 + wm * 16 + lk * 4 + r;
                const size_t ch = (size_t)b * HID + h;
                float f  = ALPHA_C * sigf(acc[0][r] + bfv) + (1.0f - ALPHA_C) * sigf(vacc[0][r] + bqv);
                float i_ = ALPHA_C * sigf(acc[1][r] + biv) + (1.0f - ALPHA_C) * sigf(vacc[1][r] + bqv);
                float g_ = ALPHA_C * tanhf_fast(acc[2][r] + buv) + (1.0f - ALPHA_C) * tanhf_fast(vacc[2][r] + bqv);
                float o_ = ALPHA_C * sigf(acc[3][r] + bov) + (1.0f - ALPHA_C) * sigf(vacc[3][r] + bqv);
                float cn = f * cxr[r] + i_ * g_;
                float hn = o_ * tanhf_fast(cn);
                cxr[r]   = cn;
                wbuf[ch] = (__bf16)hn;                 // normal store (must be coherent-visible)
                __builtin_nontemporal_store(hn, out + (size_t)t * BH + ch);
                if (t == T_STEPS - 1) {
                    out[(size_t)T_STEPS * BH + ch]      = hn;   // hx tail
                    out[(size_t)(T_STEPS + 1) * BH + ch] = cn;  // cx tail
                }
            }
        }

        // ---- grid barrier (tree) with shadow x-GEMM ----
        if (t < T_STEPS - 1) {
            __syncthreads();                            // all block stores issued + drained
            if (tid == 0) {
                __threadfence();                        // release hx/out writes device-wide
                int old = atomicAdd(cnt_slot, 1);
                if (old == 31) {
                    int o2 = atomicAdd(cnt2, 1);
                    if (o2 == 7) {                      // last block of all 256
                        #pragma unroll
                        for (int i = 0; i < 8; ++i)
                            __hip_atomic_store(bar + i * 32, 0, __ATOMIC_RELAXED, __HIP_MEMORY_SCOPE_AGENT);
                        __hip_atomic_store(cnt2, 0, __ATOMIC_RELAXED, __HIP_MEMORY_SCOPE_AGENT);
                        __hip_atomic_store(gate, t + 1, __ATOMIC_RELEASE, __HIP_MEMORY_SCOPE_AGENT);
                    }
                }
            }

            // shadow work: next step's x-part (independent of hx)
            #pragma unroll
            for (int g = 0; g < 5; ++g) xacc[g] = (f32x4){};
            xgemm(t + 1, xacc);

            if (tid == 0) {
                long spins = 0;
                while (__hip_atomic_load(gate, __ATOMIC_ACQUIRE, __HIP_MEMORY_SCOPE_AGENT) < t + 1) {
                    __builtin_amdgcn_s_sleep(2);
                    if (++spins > 200000000L) break;    // anti-hang safety valve
                }
            }
            __syncthreads();                            // block proceeds; acquire done on this CU
        }
    }
}

// ---------------- launch ----------------

extern "C" void kernel_launch(void* const* d_in, const int* in_sizes, int n_in,
                              void* d_out, int out_size, void* d_ws, size_t ws_size,
                              hipStream_t stream) {
    const float* X   = (const float*)d_in[0];
    const float* Wf  = (const float*)d_in[1];
    const float* bf_ = (const float*)d_in[2];
    const float* Wi  = (const float*)d_in[3];
    const float* bi  = (const float*)d_in[4];
    const float* Wu  = (const float*)d_in[5];
    const float* bu  = (const float*)d_in[6];
    const float* Wo  = (const float*)d_in[7];
    const float* bo  = (const float*)d_in[8];
    const float* Wq  = (const float*)d_in[9];
    const float* bq  = (const float*)d_in[10];
    const float* Wqh = (const float*)d_in[11];
    const float* bqh = (const float*)d_in[12];
    const float* thf = (const float*)d_in[13];
    const float* thi = (const float*)d_in[14];
    const float* thu = (const float*)d_in[15];
    const float* tho = (const float*)d_in[16];
    float* out = (float*)d_out;

    char*  ws  = (char*)d_ws;
    size_t off = 0;
    auto alloc = [&](size_t bytes) -> char* {
        char* p = ws + off;
        off += (bytes + 255) & ~(size_t)255;
        return p;
    };
    __bf16* Wt2  = (__bf16*)alloc((size_t)32 * 32 * 4 * 64 * 8 * 2);   // 4 MB, frag-ordered gates
    __bf16* Wtq  = (__bf16*)alloc((size_t)32 * 64 * 8 * 2);            // 32 KB, frag-ordered q
    __bf16* WqhT = (__bf16*)alloc((size_t)HID * NQV * 2);              // 8 KB
    __bf16* hx0  = (__bf16*)alloc((size_t)BATCH * HID * 2);            // 512 KB ping
    __bf16* hx1  = (__bf16*)alloc((size_t)BATCH * HID * 2);            // 512 KB pong
    int*    bar  = (int*)   alloc(512 * 4);                            // barrier state
    (void)ws_size;   // total ~5.1 MB, within proven budget

    // barrier state must be zero every call (ws is poisoned 0xAA before each call)
    zero_kernel<<<dim3(2), dim3(256), 0, stream>>>((uint32_t*)bar, 512);

    pack_w2_kernel<<<dim3(262144 / 256), dim3(256), 0, stream>>>(Wf, Wi, Wu, Wo, Wt2);
    pack_wq2_kernel<<<dim3(2048 / 256), dim3(256), 0, stream>>>(Wq, Wtq);
    pack_wqh_kernel<<<dim3((HID * NQV + 255) / 256), dim3(256), 0, stream>>>(Wqh, WqhT);

    qlstm_persistent<<<dim3(NBLK), dim3(512), 0, stream>>>(
        X, Wt2, Wtq, WqhT, bf_, bi, bu, bo, bq, bqh, thf, thi, thu, tho,
        hx0, hx1, bar, out);

    (void)in_sizes; (void)n_in; (void)out_size;
}